// Round 1
// baseline (3065.695 us; speedup 1.0000x reference)
//
#include <hip/hip_runtime.h>
#include <hip/hip_bf16.h>
#include <math.h>

#define B_ 4
#define S_ 1024
#define D_ 512
#define H_ 8
#define L_ 4
#define DFF_ 2048
#define V_ 32000
#define DK_ 64
#define KTOP 307

using bf16x8 = __attribute__((ext_vector_type(8))) __bf16;
using bf16x4 = __attribute__((ext_vector_type(4))) __bf16;
using f32x4v = __attribute__((ext_vector_type(4))) float;

// ---------------- embedding: h = tok_emb[x] + pos_emb ----------------
__global__ void embed_kernel(const int* __restrict__ x, const float* __restrict__ tok,
                             const float* __restrict__ pos, float* __restrict__ h) {
  int row = blockIdx.x;            // 0..4095 (b*S+s)
  int t = threadIdx.x;             // 128 threads x float4 = 512
  int s = row & (S_ - 1);
  int token = x[row];
  const float4* t4 = reinterpret_cast<const float4*>(tok + (size_t)token * D_);
  const float4* p4 = reinterpret_cast<const float4*>(pos + (size_t)s * D_);
  float4 a = t4[t];
  float4 b = p4[t];
  a.x += b.x; a.y += b.y; a.z += b.z; a.w += b.w;
  reinterpret_cast<float4*>(h + (size_t)row * D_)[t] = a;
}

// ---------------- layernorm (one block per row, D=512) ----------------
__global__ void ln_kernel(const float* __restrict__ xin, const float* __restrict__ g,
                          const float* __restrict__ bta, float* __restrict__ y) {
  int row = blockIdx.x;
  int t = threadIdx.x;             // 256 threads x float2
  const float2* x2 = reinterpret_cast<const float2*>(xin + (size_t)row * D_);
  float2 v = x2[t];
  float s = v.x + v.y;
  #pragma unroll
  for (int m = 1; m < 64; m <<= 1) s += __shfl_xor(s, m, 64);
  __shared__ float red[4];
  __shared__ float red2[4];
  int wid = t >> 6, lane = t & 63;
  if (lane == 0) red[wid] = s;
  __syncthreads();
  float mu = (red[0] + red[1] + red[2] + red[3]) * (1.0f / D_);
  float dx = v.x - mu, dy = v.y - mu;
  float s2 = dx * dx + dy * dy;
  #pragma unroll
  for (int m = 1; m < 64; m <<= 1) s2 += __shfl_xor(s2, m, 64);
  if (lane == 0) red2[wid] = s2;
  __syncthreads();
  float var = (red2[0] + red2[1] + red2[2] + red2[3]) * (1.0f / D_);
  float rstd = rsqrtf(var + 1e-5f);
  float2 gg = reinterpret_cast<const float2*>(g)[t];
  float2 bb = reinterpret_cast<const float2*>(bta)[t];
  float2 out;
  out.x = dx * rstd * gg.x + bb.x;
  out.y = dy * rstd * gg.y + bb.y;
  reinterpret_cast<float2*>(y + (size_t)row * D_)[t] = out;
}

// ------------- transpose fp32 [Kd][N] -> bf16 [N][Kd], batched over z -------------
__global__ void transpose_bf16_kernel(const float* __restrict__ in, __bf16* __restrict__ out,
                                      int Kd, int N) {
  __shared__ float tile[32][33];
  size_t boff = (size_t)blockIdx.z * (size_t)Kd * (size_t)N;
  int n0 = blockIdx.x * 32, k0 = blockIdx.y * 32;
  int tx = threadIdx.x & 31, ty = threadIdx.x >> 5;   // 32x8
  #pragma unroll
  for (int i = 0; i < 4; ++i)
    tile[ty + i * 8][tx] = in[boff + (size_t)(k0 + ty + i * 8) * N + n0 + tx];
  __syncthreads();
  #pragma unroll
  for (int i = 0; i < 4; ++i)
    out[boff + (size_t)(n0 + ty + i * 8) * Kd + k0 + tx] = (__bf16)tile[tx][ty + i * 8];
}

// ---------------- bf16 MFMA GEMM: out[M,N] = A[M,K] @ W + bias (+res) (+gelu) ----------------
// A fp32 row-major (converted to bf16 while staging), WT bf16 [N][K] (pre-transposed).
#define BM 128
#define BN 128
#define BK 32
#define SK 40   // padded LDS K-stride: 80B row stride = 16B aligned, banks spread

template<bool GELU_ACT, bool RES>
__global__ __launch_bounds__(256)
void gemm_kernel(const float* __restrict__ A, const __bf16* __restrict__ WT,
                 const float* __restrict__ bias, const float* __restrict__ res,
                 float* __restrict__ out, int M, int N, int Kd) {
  __shared__ __bf16 As[BM][SK];
  __shared__ __bf16 Ws[BN][SK];
  int tid = threadIdx.x;
  int lane = tid & 63, wid = tid >> 6;
  int wr = wid >> 1, wc = wid & 1;              // 2x2 waves, each 64x64
  int row0 = blockIdx.x * BM, col0 = blockIdx.y * BN;

  f32x4v acc[4][4];
  #pragma unroll
  for (int i = 0; i < 4; ++i)
    #pragma unroll
    for (int j = 0; j < 4; ++j)
      #pragma unroll
      for (int e = 0; e < 4; ++e) acc[i][j][e] = 0.0f;

  int atr = tid >> 3, atc = (tid & 7) * 4;      // A staging: 32 rows/pass, 8 thr/row
  int wnr = tid >> 2, wkc = (tid & 3) * 8;      // W staging: 64 rows/pass, 4 thr/row
  int lr = lane & 15, lk = (lane >> 4) * 8;

  for (int k0 = 0; k0 < Kd; k0 += BK) {
    #pragma unroll
    for (int it = 0; it < 4; ++it) {
      int r = atr + it * 32;
      float4 v = *reinterpret_cast<const float4*>(&A[(size_t)(row0 + r) * Kd + k0 + atc]);
      bf16x4 c;
      c[0] = (__bf16)v.x; c[1] = (__bf16)v.y; c[2] = (__bf16)v.z; c[3] = (__bf16)v.w;
      *reinterpret_cast<bf16x4*>(&As[r][atc]) = c;
    }
    #pragma unroll
    for (int it = 0; it < 2; ++it) {
      int n = wnr + it * 64;
      bf16x8 wv = *reinterpret_cast<const bf16x8*>(&WT[(size_t)(col0 + n) * Kd + k0 + wkc]);
      *reinterpret_cast<bf16x8*>(&Ws[n][wkc]) = wv;
    }
    __syncthreads();
    bf16x8 af[4], bfr[4];
    #pragma unroll
    for (int mr = 0; mr < 4; ++mr)
      af[mr] = *reinterpret_cast<const bf16x8*>(&As[wr * 64 + mr * 16 + lr][lk]);
    #pragma unroll
    for (int nc = 0; nc < 4; ++nc)
      bfr[nc] = *reinterpret_cast<const bf16x8*>(&Ws[wc * 64 + nc * 16 + lr][lk]);
    #pragma unroll
    for (int mr = 0; mr < 4; ++mr)
      #pragma unroll
      for (int nc = 0; nc < 4; ++nc)
        acc[mr][nc] = __builtin_amdgcn_mfma_f32_16x16x32_bf16(af[mr], bfr[nc], acc[mr][nc], 0, 0, 0);
    __syncthreads();
  }

  int lg = lane >> 4;
  #pragma unroll
  for (int mr = 0; mr < 4; ++mr) {
    #pragma unroll
    for (int nc = 0; nc < 4; ++nc) {
      #pragma unroll
      for (int j = 0; j < 4; ++j) {
        int r = row0 + wr * 64 + mr * 16 + lg * 4 + j;
        int c = col0 + wc * 64 + nc * 16 + lr;
        float vv = acc[mr][nc][j] + bias[c];
        if (RES) vv += res[(size_t)r * N + c];
        if (GELU_ACT) vv = 0.5f * vv * (1.0f + erff(vv * 0.70710678118654752f));
        out[(size_t)r * N + c] = vv;
      }
    }
  }
}

// ---------------- fused attention: scores -> top-307 -> softmax -> PV ----------------
// q,k,v fp32 [B,S,D] (head h occupies cols h*64..h*64+63). One block = 16 query rows.
__global__ __launch_bounds__(256)
void attn_kernel(const float* __restrict__ q, const float* __restrict__ k,
                 const float* __restrict__ v, float* __restrict__ o) {
  __shared__ float qs[16][64];
  __shared__ unsigned int sc[16][1032];   // scores -> mapped uints -> probs (in place)
  __shared__ float rs[16];
  int q0 = blockIdx.x * 16;
  int hh = blockIdx.y;
  int bb = blockIdx.z;
  int tid = threadIdx.x;

  const float* qb = q + (size_t)bb * S_ * D_ + hh * DK_;
  const float* kb = k + (size_t)bb * S_ * D_ + hh * DK_;
  const float* vb = v + (size_t)bb * S_ * D_ + hh * DK_;

  { // load q tile, pre-scaled by 1/sqrt(DK)
    int r = tid >> 4, d4 = tid & 15;
    float4 qv = *reinterpret_cast<const float4*>(&qb[(size_t)(q0 + r) * D_ + d4 * 4]);
    qv.x *= 0.125f; qv.y *= 0.125f; qv.z *= 0.125f; qv.w *= 0.125f;
    *reinterpret_cast<float4*>(&qs[r][d4 * 4]) = qv;
  }
  __syncthreads();

  { // phase 1: thread t computes scores for keys j = 4t..4t+3, all 16 rows
    int j0 = tid * 4;
    float accs[16][4];
    #pragma unroll
    for (int r = 0; r < 16; ++r)
      #pragma unroll
      for (int jl = 0; jl < 4; ++jl) accs[r][jl] = 0.0f;
    for (int d4 = 0; d4 < 16; ++d4) {
      float4 kv[4];
      #pragma unroll
      for (int jl = 0; jl < 4; ++jl)
        kv[jl] = *reinterpret_cast<const float4*>(&kb[(size_t)(j0 + jl) * D_ + d4 * 4]);
      #pragma unroll
      for (int r = 0; r < 16; ++r) {
        float4 qv = *reinterpret_cast<const float4*>(&qs[r][d4 * 4]);
        #pragma unroll
        for (int jl = 0; jl < 4; ++jl)
          accs[r][jl] += qv.x * kv[jl].x + qv.y * kv[jl].y + qv.z * kv[jl].z + qv.w * kv[jl].w;
      }
    }
    #pragma unroll
    for (int r = 0; r < 16; ++r)
      #pragma unroll
      for (int jl = 0; jl < 4; ++jl) {
        unsigned int u = __float_as_uint(accs[r][jl]);
        u = (u & 0x80000000u) ? ~u : (u | 0x80000000u);   // monotone map
        sc[r][j0 + jl] = u;
      }
  }
  __syncthreads();

  { // phase 2: per-row 307th-largest threshold (binary search on uint bits) + softmax
    int r = tid >> 4, tc = tid & 15;     // 16 threads per row
    unsigned int uv[64];
    #pragma unroll
    for (int jj = 0; jj < 64; ++jj) uv[jj] = sc[r][tc + jj * 16];
    unsigned int umax = 0u;
    #pragma unroll
    for (int jj = 0; jj < 64; ++jj) umax = (uv[jj] > umax) ? uv[jj] : umax;
    #pragma unroll
    for (int m = 1; m < 16; m <<= 1) {
      unsigned int other = (unsigned int)__shfl_xor((int)umax, m, 64);
      umax = (other > umax) ? other : umax;
    }
    unsigned int lo = 0u;
    for (int bit = 31; bit >= 0; --bit) {
      unsigned int c = lo | (1u << bit);
      int cnt = 0;
      #pragma unroll
      for (int jj = 0; jj < 64; ++jj) cnt += (uv[jj] >= c) ? 1 : 0;
      #pragma unroll
      for (int m = 1; m < 16; m <<= 1) cnt += __shfl_xor(cnt, m, 64);
      if (cnt >= KTOP) lo = c;
    }
    unsigned int ubm = (umax & 0x80000000u) ? (umax ^ 0x80000000u) : ~umax;
    float mval = __uint_as_float(ubm);
    float lsum = 0.0f;
    #pragma unroll
    for (int jj = 0; jj < 64; ++jj) {
      unsigned int u = uv[jj];
      float p = 0.0f;
      if (u >= lo) {
        unsigned int ub = (u & 0x80000000u) ? (u ^ 0x80000000u) : ~u;
        p = __expf(__uint_as_float(ub) - mval);
      }
      lsum += p;
      sc[r][tc + jj * 16] = __float_as_uint(p);
    }
    #pragma unroll
    for (int m = 1; m < 16; m <<= 1) lsum += __shfl_xor(lsum, m, 64);
    if (tc == 0) rs[r] = lsum;
  }
  __syncthreads();

  { // phase 3: o[r][:] = (P @ V) / rowsum
    int r = tid >> 4, dg = tid & 15;
    const float* pr = reinterpret_cast<const float*>(&sc[r][0]);
    float4 oa0 = {0, 0, 0, 0}, oa1 = {0, 0, 0, 0};
    for (int j = 0; j < S_; j += 2) {
      float p0 = pr[j], p1 = pr[j + 1];
      float4 v0 = *reinterpret_cast<const float4*>(&vb[(size_t)j * D_ + dg * 4]);
      float4 v1 = *reinterpret_cast<const float4*>(&vb[(size_t)(j + 1) * D_ + dg * 4]);
      oa0.x += p0 * v0.x; oa0.y += p0 * v0.y; oa0.z += p0 * v0.z; oa0.w += p0 * v0.w;
      oa1.x += p1 * v1.x; oa1.y += p1 * v1.y; oa1.z += p1 * v1.z; oa1.w += p1 * v1.w;
    }
    float inv = 1.0f / rs[r];
    float4 oa;
    oa.x = (oa0.x + oa1.x) * inv; oa.y = (oa0.y + oa1.y) * inv;
    oa.z = (oa0.z + oa1.z) * inv; oa.w = (oa0.w + oa1.w) * inv;
    float* ob = o + (size_t)bb * S_ * D_ + hh * DK_;
    *reinterpret_cast<float4*>(&ob[(size_t)(q0 + r) * D_ + dg * 4]) = oa;
  }
}

extern "C" void kernel_launch(void* const* d_in, const int* in_sizes, int n_in,
                              void* d_out, int out_size, void* d_ws, size_t ws_size,
                              hipStream_t stream) {
  (void)in_sizes; (void)n_in; (void)out_size; (void)ws_size;
  const int*   x    = (const int*)d_in[0];
  const float* tok  = (const float*)d_in[1];
  const float* pos  = (const float*)d_in[2];
  const float* Wq   = (const float*)d_in[3];
  const float* bq   = (const float*)d_in[4];
  const float* Wk   = (const float*)d_in[5];
  const float* bk   = (const float*)d_in[6];
  const float* Wv   = (const float*)d_in[7];
  const float* bv   = (const float*)d_in[8];
  const float* Wo   = (const float*)d_in[9];
  const float* bo   = (const float*)d_in[10];
  const float* g1   = (const float*)d_in[11];
  const float* be1  = (const float*)d_in[12];
  const float* g2   = (const float*)d_in[13];
  const float* be2  = (const float*)d_in[14];
  const float* W1   = (const float*)d_in[15];
  const float* b1   = (const float*)d_in[16];
  const float* Wm   = (const float*)d_in[17];
  const float* bm   = (const float*)d_in[18];
  const float* W2   = (const float*)d_in[19];
  const float* b2   = (const float*)d_in[20];
  const float* Wout = (const float*)d_in[21];
  const float* bout = (const float*)d_in[22];
  float* logits = (float*)d_out;

  const int M = B_ * S_;  // 4096
  float* ws = (float*)d_ws;
  float* h  = ws;
  float* y  = h  + (size_t)M * D_;
  float* qb = y  + (size_t)M * D_;
  float* kb = qb + (size_t)M * D_;
  float* vb = kb + (size_t)M * D_;
  float* ob = vb + (size_t)M * D_;
  float* f1 = ob + (size_t)M * D_;
  float* f2 = f1 + (size_t)M * DFF_;
  __bf16* WqT   = (__bf16*)(f2 + (size_t)M * DFF_);
  __bf16* WkT   = WqT  + (size_t)L_ * D_ * D_;
  __bf16* WvT   = WkT  + (size_t)L_ * D_ * D_;
  __bf16* WoT   = WvT  + (size_t)L_ * D_ * D_;
  __bf16* W1T   = WoT  + (size_t)L_ * D_ * D_;     // [l][DFF][D]
  __bf16* WmT   = W1T  + (size_t)L_ * D_ * DFF_;   // [l][DFF][DFF]
  __bf16* W2T   = WmT  + (size_t)L_ * DFF_ * DFF_; // [l][D][DFF]
  __bf16* WoutT = W2T  + (size_t)L_ * D_ * DFF_;   // [V][D]

  // weight transposes (fp32 -> bf16 [N][K]); cheap, once per call
  transpose_bf16_kernel<<<dim3(D_/32,  D_/32,   L_), 256, 0, stream>>>(Wq,   WqT,   D_,   D_);
  transpose_bf16_kernel<<<dim3(D_/32,  D_/32,   L_), 256, 0, stream>>>(Wk,   WkT,   D_,   D_);
  transpose_bf16_kernel<<<dim3(D_/32,  D_/32,   L_), 256, 0, stream>>>(Wv,   WvT,   D_,   D_);
  transpose_bf16_kernel<<<dim3(D_/32,  D_/32,   L_), 256, 0, stream>>>(Wo,   WoT,   D_,   D_);
  transpose_bf16_kernel<<<dim3(DFF_/32, D_/32,  L_), 256, 0, stream>>>(W1,   W1T,   D_,   DFF_);
  transpose_bf16_kernel<<<dim3(DFF_/32, DFF_/32,L_), 256, 0, stream>>>(Wm,   WmT,   DFF_, DFF_);
  transpose_bf16_kernel<<<dim3(D_/32,  DFF_/32, L_), 256, 0, stream>>>(W2,   W2T,   DFF_, D_);
  transpose_bf16_kernel<<<dim3(V_/32,  D_/32,   1 ), 256, 0, stream>>>(Wout, WoutT, D_,   V_);

  embed_kernel<<<M, 128, 0, stream>>>(x, tok, pos, h);

  for (int l = 0; l < L_; ++l) {
    ln_kernel<<<M, 256, 0, stream>>>(h, g1 + l * D_, be1 + l * D_, y);
    gemm_kernel<false,false><<<dim3(M/BM, D_/BN), 256, 0, stream>>>(
        y, WqT + (size_t)l * D_ * D_, bq + l * D_, nullptr, qb, M, D_, D_);
    gemm_kernel<false,false><<<dim3(M/BM, D_/BN), 256, 0, stream>>>(
        y, WkT + (size_t)l * D_ * D_, bk + l * D_, nullptr, kb, M, D_, D_);
    gemm_kernel<false,false><<<dim3(M/BM, D_/BN), 256, 0, stream>>>(
        y, WvT + (size_t)l * D_ * D_, bv + l * D_, nullptr, vb, M, D_, D_);
    attn_kernel<<<dim3(S_/16, H_, B_), 256, 0, stream>>>(qb, kb, vb, ob);
    gemm_kernel<false,true><<<dim3(M/BM, D_/BN), 256, 0, stream>>>(
        ob, WoT + (size_t)l * D_ * D_, bo + l * D_, h, h, M, D_, D_);
    ln_kernel<<<M, 256, 0, stream>>>(h, g2 + l * D_, be2 + l * D_, y);
    gemm_kernel<true,false><<<dim3(M/BM, DFF_/BN), 256, 0, stream>>>(
        y, W1T + (size_t)l * D_ * DFF_, b1 + l * DFF_, nullptr, f1, M, DFF_, D_);
    gemm_kernel<true,false><<<dim3(M/BM, DFF_/BN), 256, 0, stream>>>(
        f1, WmT + (size_t)l * DFF_ * DFF_, bm + l * DFF_, nullptr, f2, M, DFF_, DFF_);
    gemm_kernel<false,true><<<dim3(M/BM, D_/BN), 256, 0, stream>>>(
        f2, W2T + (size_t)l * DFF_ * D_, b2 + l * D_, h, h, M, D_, DFF_);
  }
  gemm_kernel<false,false><<<dim3(M/BM, V_/BN), 256, 0, stream>>>(
      h, WoutT, bout, nullptr, logits, M, V_, D_);
}

// Round 2
// 1950.647 us; speedup vs baseline: 1.5716x; 1.5716x over previous
//
#include <hip/hip_runtime.h>
#include <hip/hip_bf16.h>
#include <math.h>

#define B_ 4
#define S_ 1024
#define D_ 512
#define H_ 8
#define L_ 4
#define DFF_ 2048
#define V_ 32000
#define DK_ 64
#define KTOP 307

using bf16x8 = __attribute__((ext_vector_type(8))) __bf16;
using bf16x4 = __attribute__((ext_vector_type(4))) __bf16;
using f32x4v = __attribute__((ext_vector_type(4))) float;

// ---------------- embedding: h = tok_emb[x] + pos_emb ----------------
__global__ void embed_kernel(const int* __restrict__ x, const float* __restrict__ tok,
                             const float* __restrict__ pos, float* __restrict__ h) {
  int row = blockIdx.x;
  int t = threadIdx.x;             // 128 threads x float4 = 512
  int s = row & (S_ - 1);
  int token = x[row];
  const float4* t4 = reinterpret_cast<const float4*>(tok + (size_t)token * D_);
  const float4* p4 = reinterpret_cast<const float4*>(pos + (size_t)s * D_);
  float4 a = t4[t];
  float4 b = p4[t];
  a.x += b.x; a.y += b.y; a.z += b.z; a.w += b.w;
  reinterpret_cast<float4*>(h + (size_t)row * D_)[t] = a;
}

// ---------------- layernorm (one block per row, D=512) ----------------
__global__ void ln_kernel(const float* __restrict__ xin, const float* __restrict__ g,
                          const float* __restrict__ bta, float* __restrict__ y) {
  int row = blockIdx.x;
  int t = threadIdx.x;             // 256 threads x float2
  const float2* x2 = reinterpret_cast<const float2*>(xin + (size_t)row * D_);
  float2 v = x2[t];
  float s = v.x + v.y;
  #pragma unroll
  for (int m = 1; m < 64; m <<= 1) s += __shfl_xor(s, m, 64);
  __shared__ float red[4];
  __shared__ float red2[4];
  int wid = t >> 6, lane = t & 63;
  if (lane == 0) red[wid] = s;
  __syncthreads();
  float mu = (red[0] + red[1] + red[2] + red[3]) * (1.0f / D_);
  float dx = v.x - mu, dy = v.y - mu;
  float s2 = dx * dx + dy * dy;
  #pragma unroll
  for (int m = 1; m < 64; m <<= 1) s2 += __shfl_xor(s2, m, 64);
  if (lane == 0) red2[wid] = s2;
  __syncthreads();
  float var = (red2[0] + red2[1] + red2[2] + red2[3]) * (1.0f / D_);
  float rstd = rsqrtf(var + 1e-5f);
  float2 gg = reinterpret_cast<const float2*>(g)[t];
  float2 bb = reinterpret_cast<const float2*>(bta)[t];
  float2 out;
  out.x = dx * rstd * gg.x + bb.x;
  out.y = dy * rstd * gg.y + bb.y;
  reinterpret_cast<float2*>(y + (size_t)row * D_)[t] = out;
}

// ------------- transpose fp32 [Kd][N] -> bf16 [N][Kd], batched over z -------------
__global__ void transpose_bf16_kernel(const float* __restrict__ in, __bf16* __restrict__ out,
                                      int Kd, int N) {
  __shared__ float tile[32][33];
  size_t boff = (size_t)blockIdx.z * (size_t)Kd * (size_t)N;
  int n0 = blockIdx.x * 32, k0 = blockIdx.y * 32;
  int tx = threadIdx.x & 31, ty = threadIdx.x >> 5;   // 32x8
  #pragma unroll
  for (int i = 0; i < 4; ++i)
    tile[ty + i * 8][tx] = in[boff + (size_t)(k0 + ty + i * 8) * N + n0 + tx];
  __syncthreads();
  #pragma unroll
  for (int i = 0; i < 4; ++i)
    out[boff + (size_t)(n0 + ty + i * 8) * Kd + k0 + tx] = (__bf16)tile[tx][ty + i * 8];
}

// ---------------- bf16 MFMA GEMM: out[M,N] = A[M,K] @ W + bias (+res) (+gelu) ----------------
// A fp32 row-major (converted to bf16 while staging), WT bf16 [N][K] (pre-transposed).
// OMODE: 0 = fp32 row-major out, 1 = bf16 row-major out, 2 = bf16 V-transposed out
//        (vt[(b*D_ + c)*S_ + s], b = r/S_, s = r%S_)
#define BM 128
#define BN 128
#define BK 32
#define SK 40   // padded LDS K-stride

template<int OMODE, bool GELU_ACT, bool RES>
__global__ __launch_bounds__(256)
void gemm_kernel(const float* __restrict__ A, const __bf16* __restrict__ WT,
                 const float* __restrict__ bias, const float* __restrict__ res,
                 void* __restrict__ outp, int M, int N, int Kd) {
  __shared__ __bf16 As[BM][SK];
  __shared__ __bf16 Ws[BN][SK];
  int tid = threadIdx.x;
  int lane = tid & 63, wid = tid >> 6;
  int wr = wid >> 1, wc = wid & 1;              // 2x2 waves, each 64x64
  int row0 = blockIdx.x * BM, col0 = blockIdx.y * BN;

  f32x4v acc[4][4];
  #pragma unroll
  for (int i = 0; i < 4; ++i)
    #pragma unroll
    for (int j = 0; j < 4; ++j)
      #pragma unroll
      for (int e = 0; e < 4; ++e) acc[i][j][e] = 0.0f;

  int atr = tid >> 3, atc = (tid & 7) * 4;
  int wnr = tid >> 2, wkc = (tid & 3) * 8;
  int lr = lane & 15, lk = (lane >> 4) * 8;

  for (int k0 = 0; k0 < Kd; k0 += BK) {
    #pragma unroll
    for (int it = 0; it < 4; ++it) {
      int r = atr + it * 32;
      float4 v = *reinterpret_cast<const float4*>(&A[(size_t)(row0 + r) * Kd + k0 + atc]);
      bf16x4 c;
      c[0] = (__bf16)v.x; c[1] = (__bf16)v.y; c[2] = (__bf16)v.z; c[3] = (__bf16)v.w;
      *reinterpret_cast<bf16x4*>(&As[r][atc]) = c;
    }
    #pragma unroll
    for (int it = 0; it < 2; ++it) {
      int n = wnr + it * 64;
      bf16x8 wv = *reinterpret_cast<const bf16x8*>(&WT[(size_t)(col0 + n) * Kd + k0 + wkc]);
      *reinterpret_cast<bf16x8*>(&Ws[n][wkc]) = wv;
    }
    __syncthreads();
    bf16x8 af[4], bfr[4];
    #pragma unroll
    for (int mr = 0; mr < 4; ++mr)
      af[mr] = *reinterpret_cast<const bf16x8*>(&As[wr * 64 + mr * 16 + lr][lk]);
    #pragma unroll
    for (int nc = 0; nc < 4; ++nc)
      bfr[nc] = *reinterpret_cast<const bf16x8*>(&Ws[wc * 64 + nc * 16 + lr][lk]);
    #pragma unroll
    for (int mr = 0; mr < 4; ++mr)
      #pragma unroll
      for (int nc = 0; nc < 4; ++nc)
        acc[mr][nc] = __builtin_amdgcn_mfma_f32_16x16x32_bf16(af[mr], bfr[nc], acc[mr][nc], 0, 0, 0);
    __syncthreads();
  }

  int lg = lane >> 4;
  #pragma unroll
  for (int mr = 0; mr < 4; ++mr) {
    #pragma unroll
    for (int nc = 0; nc < 4; ++nc) {
      int c = col0 + wc * 64 + nc * 16 + lr;
      int rbase = row0 + wr * 64 + mr * 16 + lg * 4;
      float vv[4];
      #pragma unroll
      for (int j = 0; j < 4; ++j) {
        float t = acc[mr][nc][j] + bias[c];
        if (RES) t += res[(size_t)(rbase + j) * N + c];
        if (GELU_ACT) t = 0.5f * t * (1.0f + erff(t * 0.70710678118654752f));
        vv[j] = t;
      }
      if (OMODE == 0) {
        float* out = (float*)outp;
        #pragma unroll
        for (int j = 0; j < 4; ++j) out[(size_t)(rbase + j) * N + c] = vv[j];
      } else if (OMODE == 1) {
        __bf16* out = (__bf16*)outp;
        #pragma unroll
        for (int j = 0; j < 4; ++j) out[(size_t)(rbase + j) * N + c] = (__bf16)vv[j];
      } else {
        __bf16* out = (__bf16*)outp;
        int b = rbase >> 10, s0 = rbase & (S_ - 1);
        bf16x4 pk;
        #pragma unroll
        for (int j = 0; j < 4; ++j) pk[j] = (__bf16)vv[j];
        *reinterpret_cast<bf16x4*>(&out[((size_t)b * D_ + c) * S_ + s0]) = pk;
      }
    }
  }
}

// ---------------- fused attention: MFMA scores -> top-307 -> softmax -> MFMA PV ----------------
// q,k bf16 [B*S][D] row-major; vt bf16 [B][D][S] (per-column, transposed); o fp32 [B*S][D].
// One block = 16 query rows of one (b,h); 4 waves.
__global__ __launch_bounds__(256)
void attn_kernel(const __bf16* __restrict__ qm, const __bf16* __restrict__ km,
                 const __bf16* __restrict__ vt, float* __restrict__ o) {
  __shared__ unsigned int sc[16][1036];   // fp32-mapped scores; reused as bf16 P[16][1032]
  __shared__ float rs[16];
  const int q0 = blockIdx.x * 16;
  const int hh = blockIdx.y;
  const int bb = blockIdx.z;
  const int tid = threadIdx.x;
  const int lane = tid & 63, w = tid >> 6;
  const int lr = lane & 15, lg = lane >> 4;

  // Q fragments (A operand), held in registers for the whole block
  const __bf16* qrow = qm + ((size_t)(bb * S_ + q0 + lr)) * D_ + hh * DK_;
  bf16x8 qf0 = *reinterpret_cast<const bf16x8*>(qrow + lg * 8);
  bf16x8 qf1 = *reinterpret_cast<const bf16x8*>(qrow + 32 + lg * 8);

  // ---- phase 1: scores via MFMA, K fragments straight from global (L2-resident) ----
  const __bf16* kbase = km + ((size_t)bb * S_) * D_ + hh * DK_;
  #pragma unroll 4
  for (int kt = 0; kt < 16; ++kt) {
    int key0 = kt * 64 + w * 16;
    const __bf16* krow = kbase + (size_t)(key0 + lr) * D_;
    bf16x8 kf0 = *reinterpret_cast<const bf16x8*>(krow + lg * 8);
    bf16x8 kf1 = *reinterpret_cast<const bf16x8*>(krow + 32 + lg * 8);
    f32x4v d = {0.0f, 0.0f, 0.0f, 0.0f};
    d = __builtin_amdgcn_mfma_f32_16x16x32_bf16(qf0, kf0, d, 0, 0, 0);
    d = __builtin_amdgcn_mfma_f32_16x16x32_bf16(qf1, kf1, d, 0, 0, 0);
    #pragma unroll
    for (int j = 0; j < 4; ++j) {
      float s = d[j] * 0.125f;
      unsigned int u = __float_as_uint(s);
      u = (u & 0x80000000u) ? ~u : (u | 0x80000000u);   // monotone map
      sc[lg * 4 + j][key0 + lr] = u;
    }
  }
  __syncthreads();

  // ---- phase 2: per-row top-307 threshold + softmax -> bf16 P (LDS overlay) ----
  {
    int r = tid >> 4, tc = tid & 15;     // 16 threads per row; thread owns 16 groups of 4 keys
    uint4 uv4[16];
    #pragma unroll
    for (int g = 0; g < 16; ++g)
      uv4[g] = *reinterpret_cast<const uint4*>(&sc[r][tc * 4 + g * 64]);
    __syncthreads();   // all mapped scores now in registers; sc memory free for P

    unsigned int umax = 0u;
    #pragma unroll
    for (int g = 0; g < 16; ++g) {
      unsigned int m0 = uv4[g].x > uv4[g].y ? uv4[g].x : uv4[g].y;
      unsigned int m1 = uv4[g].z > uv4[g].w ? uv4[g].z : uv4[g].w;
      unsigned int m2 = m0 > m1 ? m0 : m1;
      umax = m2 > umax ? m2 : umax;
    }
    #pragma unroll
    for (int m = 1; m < 16; m <<= 1) {
      unsigned int other = (unsigned int)__shfl_xor((int)umax, m, 64);
      umax = other > umax ? other : umax;
    }
    unsigned int lo = 0u;
    for (int bit = 31; bit >= 0; --bit) {
      unsigned int c = lo | (1u << bit);
      int cnt = 0;
      #pragma unroll
      for (int g = 0; g < 16; ++g) {
        cnt += (uv4[g].x >= c) ? 1 : 0;
        cnt += (uv4[g].y >= c) ? 1 : 0;
        cnt += (uv4[g].z >= c) ? 1 : 0;
        cnt += (uv4[g].w >= c) ? 1 : 0;
      }
      #pragma unroll
      for (int m = 1; m < 16; m <<= 1) cnt += __shfl_xor(cnt, m, 64);
      if (cnt >= KTOP) lo = c;
    }
    unsigned int ubm = (umax & 0x80000000u) ? (umax ^ 0x80000000u) : ~umax;
    float mval = __uint_as_float(ubm);

    __bf16* P = reinterpret_cast<__bf16*>(&sc[0][0]);   // [16][1032]
    float lsum = 0.0f;
    #pragma unroll
    for (int g = 0; g < 16; ++g) {
      unsigned int uu[4] = {uv4[g].x, uv4[g].y, uv4[g].z, uv4[g].w};
      bf16x4 pk;
      #pragma unroll
      for (int e = 0; e < 4; ++e) {
        float p = 0.0f;
        if (uu[e] >= lo) {
          unsigned int ub = (uu[e] & 0x80000000u) ? (uu[e] ^ 0x80000000u) : ~uu[e];
          p = __expf(__uint_as_float(ub) - mval);
        }
        pk[e] = (__bf16)p;
        lsum += (float)pk[e];
      }
      *reinterpret_cast<bf16x4*>(&P[(size_t)r * 1032 + tc * 4 + g * 64]) = pk;
    }
    #pragma unroll
    for (int m = 1; m < 16; m <<= 1) lsum += __shfl_xor(lsum, m, 64);
    if (tc == 0) rs[r] = lsum;
  }
  __syncthreads();

  // ---- phase 3: o = (P @ V) / rowsum via MFMA; V^T fragments straight from global ----
  {
    const __bf16* P = reinterpret_cast<const __bf16*>(&sc[0][0]);
    const __bf16* vbase = vt + ((size_t)bb * D_ + hh * DK_ + w * 16 + lr) * S_;
    const __bf16* prow = P + (size_t)lr * 1032;
    f32x4v oacc = {0.0f, 0.0f, 0.0f, 0.0f};
    #pragma unroll 4
    for (int kt = 0; kt < 32; ++kt) {
      bf16x8 a = *reinterpret_cast<const bf16x8*>(prow + kt * 32 + lg * 8);
      bf16x8 b = *reinterpret_cast<const bf16x8*>(vbase + kt * 32 + lg * 8);
      oacc = __builtin_amdgcn_mfma_f32_16x16x32_bf16(a, b, oacc, 0, 0, 0);
    }
    #pragma unroll
    for (int j = 0; j < 4; ++j) {
      int qr = lg * 4 + j;
      float ov = oacc[j] / rs[qr];
      o[((size_t)(bb * S_ + q0 + qr)) * D_ + hh * DK_ + w * 16 + lr] = ov;
    }
  }
}

extern "C" void kernel_launch(void* const* d_in, const int* in_sizes, int n_in,
                              void* d_out, int out_size, void* d_ws, size_t ws_size,
                              hipStream_t stream) {
  (void)in_sizes; (void)n_in; (void)out_size; (void)ws_size;
  const int*   x    = (const int*)d_in[0];
  const float* tok  = (const float*)d_in[1];
  const float* pos  = (const float*)d_in[2];
  const float* Wq   = (const float*)d_in[3];
  const float* bq   = (const float*)d_in[4];
  const float* Wk   = (const float*)d_in[5];
  const float* bk   = (const float*)d_in[6];
  const float* Wv   = (const float*)d_in[7];
  const float* bv   = (const float*)d_in[8];
  const float* Wo   = (const float*)d_in[9];
  const float* bo   = (const float*)d_in[10];
  const float* g1   = (const float*)d_in[11];
  const float* be1  = (const float*)d_in[12];
  const float* g2   = (const float*)d_in[13];
  const float* be2  = (const float*)d_in[14];
  const float* W1   = (const float*)d_in[15];
  const float* b1   = (const float*)d_in[16];
  const float* Wm   = (const float*)d_in[17];
  const float* bm   = (const float*)d_in[18];
  const float* W2   = (const float*)d_in[19];
  const float* b2   = (const float*)d_in[20];
  const float* Wout = (const float*)d_in[21];
  const float* bout = (const float*)d_in[22];
  float* logits = (float*)d_out;

  const int M = B_ * S_;  // 4096
  float* ws = (float*)d_ws;
  float* h  = ws;
  float* y  = h  + (size_t)M * D_;
  float* ob = y  + (size_t)M * D_;
  float* f1 = ob + (size_t)M * D_;
  float* f2 = f1 + (size_t)M * DFF_;
  __bf16* qb16 = (__bf16*)(f2 + (size_t)M * DFF_);
  __bf16* kb16 = qb16 + (size_t)M * D_;
  __bf16* vt16 = kb16 + (size_t)M * D_;               // [B][D][S]
  __bf16* WqT  = vt16 + (size_t)M * D_;
  __bf16* WkT  = WqT  + (size_t)L_ * D_ * D_;
  __bf16* WvT  = WkT  + (size_t)L_ * D_ * D_;
  __bf16* WoT  = WvT  + (size_t)L_ * D_ * D_;
  __bf16* W1T  = WoT  + (size_t)L_ * D_ * D_;     // [l][DFF][D]
  __bf16* WmT  = W1T  + (size_t)L_ * D_ * DFF_;   // [l][DFF][DFF]
  __bf16* W2T  = WmT  + (size_t)L_ * DFF_ * DFF_; // [l][D][DFF]
  __bf16* WoutT = W2T + (size_t)L_ * D_ * DFF_;   // [V][D]

  transpose_bf16_kernel<<<dim3(D_/32,  D_/32,   L_), 256, 0, stream>>>(Wq,   WqT,   D_,   D_);
  transpose_bf16_kernel<<<dim3(D_/32,  D_/32,   L_), 256, 0, stream>>>(Wk,   WkT,   D_,   D_);
  transpose_bf16_kernel<<<dim3(D_/32,  D_/32,   L_), 256, 0, stream>>>(Wv,   WvT,   D_,   D_);
  transpose_bf16_kernel<<<dim3(D_/32,  D_/32,   L_), 256, 0, stream>>>(Wo,   WoT,   D_,   D_);
  transpose_bf16_kernel<<<dim3(DFF_/32, D_/32,  L_), 256, 0, stream>>>(W1,   W1T,   D_,   DFF_);
  transpose_bf16_kernel<<<dim3(DFF_/32, DFF_/32,L_), 256, 0, stream>>>(Wm,   WmT,   DFF_, DFF_);
  transpose_bf16_kernel<<<dim3(D_/32,  DFF_/32, L_), 256, 0, stream>>>(W2,   W2T,   DFF_, D_);
  transpose_bf16_kernel<<<dim3(V_/32,  D_/32,   1 ), 256, 0, stream>>>(Wout, WoutT, D_,   V_);

  embed_kernel<<<M, 128, 0, stream>>>(x, tok, pos, h);

  for (int l = 0; l < L_; ++l) {
    ln_kernel<<<M, 256, 0, stream>>>(h, g1 + l * D_, be1 + l * D_, y);
    gemm_kernel<1,false,false><<<dim3(M/BM, D_/BN), 256, 0, stream>>>(
        y, WqT + (size_t)l * D_ * D_, bq + l * D_, nullptr, qb16, M, D_, D_);
    gemm_kernel<1,false,false><<<dim3(M/BM, D_/BN), 256, 0, stream>>>(
        y, WkT + (size_t)l * D_ * D_, bk + l * D_, nullptr, kb16, M, D_, D_);
    gemm_kernel<2,false,false><<<dim3(M/BM, D_/BN), 256, 0, stream>>>(
        y, WvT + (size_t)l * D_ * D_, bv + l * D_, nullptr, vt16, M, D_, D_);
    attn_kernel<<<dim3(S_/16, H_, B_), 256, 0, stream>>>(qb16, kb16, vt16, ob);
    gemm_kernel<0,false,true><<<dim3(M/BM, D_/BN), 256, 0, stream>>>(
        ob, WoT + (size_t)l * D_ * D_, bo + l * D_, h, h, M, D_, D_);
    ln_kernel<<<M, 256, 0, stream>>>(h, g2 + l * D_, be2 + l * D_, y);
    gemm_kernel<0,true,false><<<dim3(M/BM, DFF_/BN), 256, 0, stream>>>(
        y, W1T + (size_t)l * D_ * DFF_, b1 + l * DFF_, nullptr, f1, M, DFF_, D_);
    gemm_kernel<0,true,false><<<dim3(M/BM, DFF_/BN), 256, 0, stream>>>(
        f1, WmT + (size_t)l * DFF_ * DFF_, bm + l * DFF_, nullptr, f2, M, DFF_, DFF_);
    gemm_kernel<0,false,true><<<dim3(M/BM, D_/BN), 256, 0, stream>>>(
        f2, W2T + (size_t)l * DFF_ * D_, b2 + l * D_, h, h, M, D_, DFF_);
  }
  gemm_kernel<0,false,false><<<dim3(M/BM, V_/BN), 256, 0, stream>>>(
      h, WoutT, bout, nullptr, logits, M, V_, D_);
}

// Round 3
// 1675.704 us; speedup vs baseline: 1.8295x; 1.1641x over previous
//
#include <hip/hip_runtime.h>
#include <hip/hip_bf16.h>
#include <math.h>

#define B_ 4
#define S_ 1024
#define D_ 512
#define H_ 8
#define L_ 4
#define DFF_ 2048
#define V_ 32000
#define DK_ 64
#define KTOP 307

using bf16x8 = __attribute__((ext_vector_type(8))) __bf16;
using bf16x4 = __attribute__((ext_vector_type(4))) __bf16;
using bf16x2 = __attribute__((ext_vector_type(2))) __bf16;
using f32x4v = __attribute__((ext_vector_type(4))) float;

__device__ __forceinline__ void gload_lds16(const __bf16* g, __bf16* l) {
  __builtin_amdgcn_global_load_lds(
      (const __attribute__((address_space(1))) void*)g,
      (__attribute__((address_space(3))) void*)l, 16, 0, 0);
}

// ---------------- embedding: h = tok_emb[x] + pos_emb ----------------
__global__ void embed_kernel(const int* __restrict__ x, const float* __restrict__ tok,
                             const float* __restrict__ pos, float* __restrict__ h) {
  int row = blockIdx.x;
  int t = threadIdx.x;             // 128 threads x float4 = 512
  int s = row & (S_ - 1);
  int token = x[row];
  const float4* t4 = reinterpret_cast<const float4*>(tok + (size_t)token * D_);
  const float4* p4 = reinterpret_cast<const float4*>(pos + (size_t)s * D_);
  float4 a = t4[t];
  float4 b = p4[t];
  a.x += b.x; a.y += b.y; a.z += b.z; a.w += b.w;
  reinterpret_cast<float4*>(h + (size_t)row * D_)[t] = a;
}

// ---------------- layernorm (one block per row, D=512), bf16 out ----------------
__global__ void ln_kernel(const float* __restrict__ xin, const float* __restrict__ g,
                          const float* __restrict__ bta, __bf16* __restrict__ y) {
  int row = blockIdx.x;
  int t = threadIdx.x;             // 256 threads x float2
  const float2* x2 = reinterpret_cast<const float2*>(xin + (size_t)row * D_);
  float2 v = x2[t];
  float s = v.x + v.y;
  #pragma unroll
  for (int m = 1; m < 64; m <<= 1) s += __shfl_xor(s, m, 64);
  __shared__ float red[4];
  __shared__ float red2[4];
  int wid = t >> 6, lane = t & 63;
  if (lane == 0) red[wid] = s;
  __syncthreads();
  float mu = (red[0] + red[1] + red[2] + red[3]) * (1.0f / D_);
  float dx = v.x - mu, dy = v.y - mu;
  float s2 = dx * dx + dy * dy;
  #pragma unroll
  for (int m = 1; m < 64; m <<= 1) s2 += __shfl_xor(s2, m, 64);
  if (lane == 0) red2[wid] = s2;
  __syncthreads();
  float var = (red2[0] + red2[1] + red2[2] + red2[3]) * (1.0f / D_);
  float rstd = rsqrtf(var + 1e-5f);
  float2 gg = reinterpret_cast<const float2*>(g)[t];
  float2 bb = reinterpret_cast<const float2*>(bta)[t];
  bf16x2 o2;
  o2[0] = (__bf16)(dx * rstd * gg.x + bb.x);
  o2[1] = (__bf16)(dy * rstd * gg.y + bb.y);
  *reinterpret_cast<bf16x2*>(y + (size_t)row * D_ + t * 2) = o2;
}

// ------------- transpose fp32 [Kd][N] -> bf16 [N][Kd], batched over z -------------
__global__ void transpose_bf16_kernel(const float* __restrict__ in, __bf16* __restrict__ out,
                                      int Kd, int N, long in_bstride, long out_bstride) {
  __shared__ float tile[32][33];
  const float* ib = in + (size_t)blockIdx.z * in_bstride;
  __bf16* ob = out + (size_t)blockIdx.z * out_bstride;
  int n0 = blockIdx.x * 32, k0 = blockIdx.y * 32;
  int tx = threadIdx.x & 31, ty = threadIdx.x >> 5;   // 32x8
  #pragma unroll
  for (int i = 0; i < 4; ++i)
    tile[ty + i * 8][tx] = ib[(size_t)(k0 + ty + i * 8) * N + n0 + tx];
  __syncthreads();
  #pragma unroll
  for (int i = 0; i < 4; ++i)
    ob[(size_t)(n0 + ty + i * 8) * Kd + k0 + tx] = (__bf16)tile[tx][ty + i * 8];
}

// ---------------- bias concat for fused QKV ----------------
__global__ void concat_bias_kernel(const float* __restrict__ bq, const float* __restrict__ bk,
                                   const float* __restrict__ bv, float* __restrict__ bqkv) {
  int i = blockIdx.x * 256 + threadIdx.x;   // L_*1536
  int l = i / 1536, c = i - l * 1536;
  float v = (c < 512) ? bq[l * 512 + c]
          : (c < 1024) ? bk[l * 512 + c - 512]
                       : bv[l * 512 + c - 1024];
  bqkv[i] = v;
}

// ---------------- bf16 MFMA GEMM (m97 structure): out = A @ W^T + bias ----------------
// A bf16 row-major [M][Kd]; WT bf16 [N][Kd]. global_load_lds width-16 staging,
// linear LDS [128][32], 2-barrier K-loop, 4 waves, 4x4 16x16x32 acc per wave.
// OMODE: 0 fp32 out | 1 bf16 out | 3 fp32 out + bf16 out2 | 4 fused-QKV
//        (outp=q bf16 [M][512], outp2=k bf16 [M][512], outp3=vt bf16 [B][D][S])
#define BM 128
#define BN 128
#define BK 32

template<int OMODE, bool GELU_ACT, bool RES>
__global__ __launch_bounds__(256)
void gemm_bf16_kernel(const __bf16* __restrict__ A, const __bf16* __restrict__ WT,
                      const float* __restrict__ bias, const float* __restrict__ res,
                      void* __restrict__ outp, void* __restrict__ outp2, void* __restrict__ outp3,
                      int M, int N, int Kd) {
  __shared__ __bf16 As[BM * BK];
  __shared__ __bf16 Ws[BN * BK];
  int tid = threadIdx.x;
  int lane = tid & 63, w = tid >> 6;
  int wr = w >> 1, wc = w & 1;
  int lr = lane & 15, lg = lane >> 4;
  int row0 = blockIdx.x * BM, col0 = blockIdx.y * BN;

  int srow = lane >> 2;        // 0..15: row within the wave's 16-row stripe
  int schunk = lane & 3;       // 16B chunk within a 64B row
  const __bf16* Abase = A + (size_t)row0 * Kd + (size_t)srow * Kd + schunk * 8;
  const __bf16* Wbase = WT + (size_t)col0 * Kd + (size_t)srow * Kd + schunk * 8;

  f32x4v acc[4][4];
  #pragma unroll
  for (int i = 0; i < 4; ++i)
    #pragma unroll
    for (int j = 0; j < 4; ++j)
      #pragma unroll
      for (int e = 0; e < 4; ++e) acc[i][j][e] = 0.0f;

  for (int k0 = 0; k0 < Kd; k0 += BK) {
    #pragma unroll
    for (int p = 0; p < 2; ++p) {
      int r0 = p * 64 + w * 16;
      gload_lds16(Abase + (size_t)r0 * Kd + k0, &As[r0 * BK]);
      gload_lds16(Wbase + (size_t)r0 * Kd + k0, &Ws[r0 * BK]);
    }
    __syncthreads();   // drains vmcnt(0) then barrier
    bf16x8 af[4], bfr[4];
    #pragma unroll
    for (int mr = 0; mr < 4; ++mr)
      af[mr] = *reinterpret_cast<const bf16x8*>(&As[(wr * 64 + mr * 16 + lr) * BK + lg * 8]);
    #pragma unroll
    for (int nc = 0; nc < 4; ++nc)
      bfr[nc] = *reinterpret_cast<const bf16x8*>(&Ws[(wc * 64 + nc * 16 + lr) * BK + lg * 8]);
    #pragma unroll
    for (int mr = 0; mr < 4; ++mr)
      #pragma unroll
      for (int nc = 0; nc < 4; ++nc)
        acc[mr][nc] = __builtin_amdgcn_mfma_f32_16x16x32_bf16(af[mr], bfr[nc], acc[mr][nc], 0, 0, 0);
    __syncthreads();
  }

  #pragma unroll
  for (int mr = 0; mr < 4; ++mr) {
    #pragma unroll
    for (int nc = 0; nc < 4; ++nc) {
      int c = col0 + wc * 64 + nc * 16 + lr;
      int rb = row0 + wr * 64 + mr * 16 + lg * 4;
      float vv[4];
      #pragma unroll
      for (int j = 0; j < 4; ++j) {
        float t = acc[mr][nc][j] + bias[c];
        if (RES) t += res[(size_t)(rb + j) * N + c];
        if (GELU_ACT) t = 0.5f * t * (1.0f + erff(t * 0.70710678118654752f));
        vv[j] = t;
      }
      if (OMODE == 0) {
        float* out = (float*)outp;
        #pragma unroll
        for (int j = 0; j < 4; ++j) out[(size_t)(rb + j) * N + c] = vv[j];
      } else if (OMODE == 1) {
        __bf16* out = (__bf16*)outp;
        #pragma unroll
        for (int j = 0; j < 4; ++j) out[(size_t)(rb + j) * N + c] = (__bf16)vv[j];
      } else if (OMODE == 3) {
        float* out = (float*)outp;
        __bf16* out2 = (__bf16*)outp2;
        #pragma unroll
        for (int j = 0; j < 4; ++j) {
          out[(size_t)(rb + j) * N + c] = vv[j];
          out2[(size_t)(rb + j) * N + c] = (__bf16)vv[j];
        }
      } else {  // OMODE 4: fused QKV epilogue
        if (col0 < 512) {
          __bf16* out = (__bf16*)outp;
          #pragma unroll
          for (int j = 0; j < 4; ++j) out[(size_t)(rb + j) * D_ + c] = (__bf16)vv[j];
        } else if (col0 < 1024) {
          __bf16* out = (__bf16*)outp2;
          #pragma unroll
          for (int j = 0; j < 4; ++j) out[(size_t)(rb + j) * D_ + (c - 512)] = (__bf16)vv[j];
        } else {
          __bf16* out = (__bf16*)outp3;   // vt [B][D][S]
          int b = rb >> 10, s0 = rb & (S_ - 1);
          bf16x4 pk;
          #pragma unroll
          for (int j = 0; j < 4; ++j) pk[j] = (__bf16)vv[j];
          *reinterpret_cast<bf16x4*>(&out[((size_t)b * D_ + (c - 1024)) * S_ + s0]) = pk;
        }
      }
    }
  }
}

// ---------------- fused attention: MFMA scores -> top-307 -> softmax -> MFMA PV ----------------
// q,k bf16 [B*S][D] row-major; vt bf16 [B][D][S]; o bf16 [B*S][D].
__global__ __launch_bounds__(256)
void attn_kernel(const __bf16* __restrict__ qm, const __bf16* __restrict__ km,
                 const __bf16* __restrict__ vt, __bf16* __restrict__ o) {
  __shared__ unsigned int sc[16][1036];   // fp32-mapped scores; reused as bf16 P[16][1032]
  __shared__ float rs[16];
  const int q0 = blockIdx.x * 16;
  const int hh = blockIdx.y;
  const int bb = blockIdx.z;
  const int tid = threadIdx.x;
  const int lane = tid & 63, w = tid >> 6;
  const int lr = lane & 15, lg = lane >> 4;

  const __bf16* qrow = qm + ((size_t)(bb * S_ + q0 + lr)) * D_ + hh * DK_;
  bf16x8 qf0 = *reinterpret_cast<const bf16x8*>(qrow + lg * 8);
  bf16x8 qf1 = *reinterpret_cast<const bf16x8*>(qrow + 32 + lg * 8);

  // ---- phase 1: scores via MFMA, K fragments straight from global (L2-resident) ----
  const __bf16* kbase = km + ((size_t)bb * S_) * D_ + hh * DK_;
  #pragma unroll 4
  for (int kt = 0; kt < 16; ++kt) {
    int key0 = kt * 64 + w * 16;
    const __bf16* krow = kbase + (size_t)(key0 + lr) * D_;
    bf16x8 kf0 = *reinterpret_cast<const bf16x8*>(krow + lg * 8);
    bf16x8 kf1 = *reinterpret_cast<const bf16x8*>(krow + 32 + lg * 8);
    f32x4v d = {0.0f, 0.0f, 0.0f, 0.0f};
    d = __builtin_amdgcn_mfma_f32_16x16x32_bf16(qf0, kf0, d, 0, 0, 0);
    d = __builtin_amdgcn_mfma_f32_16x16x32_bf16(qf1, kf1, d, 0, 0, 0);
    #pragma unroll
    for (int j = 0; j < 4; ++j) {
      float s = d[j] * 0.125f;
      unsigned int u = __float_as_uint(s);
      u = (u & 0x80000000u) ? ~u : (u | 0x80000000u);   // monotone map
      sc[lg * 4 + j][key0 + lr] = u;
    }
  }
  __syncthreads();

  // ---- phase 2: per-row top-307 threshold + softmax -> bf16 P (LDS overlay) ----
  {
    int r = tid >> 4, tc = tid & 15;
    uint4 uv4[16];
    #pragma unroll
    for (int g = 0; g < 16; ++g)
      uv4[g] = *reinterpret_cast<const uint4*>(&sc[r][tc * 4 + g * 64]);
    __syncthreads();   // scores in registers; sc memory free for P

    unsigned int umax = 0u;
    #pragma unroll
    for (int g = 0; g < 16; ++g) {
      unsigned int m0 = uv4[g].x > uv4[g].y ? uv4[g].x : uv4[g].y;
      unsigned int m1 = uv4[g].z > uv4[g].w ? uv4[g].z : uv4[g].w;
      unsigned int m2 = m0 > m1 ? m0 : m1;
      umax = m2 > umax ? m2 : umax;
    }
    #pragma unroll
    for (int m = 1; m < 16; m <<= 1) {
      unsigned int other = (unsigned int)__shfl_xor((int)umax, m, 64);
      umax = other > umax ? other : umax;
    }
    unsigned int lo = 0u;
    for (int bit = 31; bit >= 0; --bit) {
      unsigned int c = lo | (1u << bit);
      int cnt = 0;
      #pragma unroll
      for (int g = 0; g < 16; ++g) {
        cnt += (uv4[g].x >= c) ? 1 : 0;
        cnt += (uv4[g].y >= c) ? 1 : 0;
        cnt += (uv4[g].z >= c) ? 1 : 0;
        cnt += (uv4[g].w >= c) ? 1 : 0;
      }
      #pragma unroll
      for (int m = 1; m < 16; m <<= 1) cnt += __shfl_xor(cnt, m, 64);
      if (cnt >= KTOP) lo = c;
    }
    unsigned int ubm = (umax & 0x80000000u) ? (umax ^ 0x80000000u) : ~umax;
    float mval = __uint_as_float(ubm);

    __bf16* P = reinterpret_cast<__bf16*>(&sc[0][0]);   // [16][1032]
    float lsum = 0.0f;
    #pragma unroll
    for (int g = 0; g < 16; ++g) {
      unsigned int uu[4] = {uv4[g].x, uv4[g].y, uv4[g].z, uv4[g].w};
      bf16x4 pk;
      #pragma unroll
      for (int e = 0; e < 4; ++e) {
        float p = 0.0f;
        if (uu[e] >= lo) {
          unsigned int ub = (uu[e] & 0x80000000u) ? (uu[e] ^ 0x80000000u) : ~uu[e];
          p = __expf(__uint_as_float(ub) - mval);
        }
        pk[e] = (__bf16)p;
        lsum += (float)pk[e];
      }
      *reinterpret_cast<bf16x4*>(&P[(size_t)r * 1032 + tc * 4 + g * 64]) = pk;
    }
    #pragma unroll
    for (int m = 1; m < 16; m <<= 1) lsum += __shfl_xor(lsum, m, 64);
    if (tc == 0) rs[r] = lsum;
  }
  __syncthreads();

  // ---- phase 3: o = (P @ V) / rowsum via MFMA; V^T fragments straight from global ----
  {
    const __bf16* P = reinterpret_cast<const __bf16*>(&sc[0][0]);
    const __bf16* vbase = vt + ((size_t)bb * D_ + hh * DK_ + w * 16 + lr) * S_;
    const __bf16* prow = P + (size_t)lr * 1032;
    f32x4v oacc = {0.0f, 0.0f, 0.0f, 0.0f};
    #pragma unroll 4
    for (int kt = 0; kt < 32; ++kt) {
      bf16x8 a = *reinterpret_cast<const bf16x8*>(prow + kt * 32 + lg * 8);
      bf16x8 b = *reinterpret_cast<const bf16x8*>(vbase + kt * 32 + lg * 8);
      oacc = __builtin_amdgcn_mfma_f32_16x16x32_bf16(a, b, oacc, 0, 0, 0);
    }
    #pragma unroll
    for (int j = 0; j < 4; ++j) {
      int qr = lg * 4 + j;
      float ov = oacc[j] / rs[qr];
      o[((size_t)(bb * S_ + q0 + qr)) * D_ + hh * DK_ + w * 16 + lr] = (__bf16)ov;
    }
  }
}

extern "C" void kernel_launch(void* const* d_in, const int* in_sizes, int n_in,
                              void* d_out, int out_size, void* d_ws, size_t ws_size,
                              hipStream_t stream) {
  (void)in_sizes; (void)n_in; (void)out_size; (void)ws_size;
  const int*   x    = (const int*)d_in[0];
  const float* tok  = (const float*)d_in[1];
  const float* pos  = (const float*)d_in[2];
  const float* Wq   = (const float*)d_in[3];
  const float* bq   = (const float*)d_in[4];
  const float* Wk   = (const float*)d_in[5];
  const float* bk   = (const float*)d_in[6];
  const float* Wv   = (const float*)d_in[7];
  const float* bv   = (const float*)d_in[8];
  const float* Wo   = (const float*)d_in[9];
  const float* bo   = (const float*)d_in[10];
  const float* g1   = (const float*)d_in[11];
  const float* be1  = (const float*)d_in[12];
  const float* g2   = (const float*)d_in[13];
  const float* be2  = (const float*)d_in[14];
  const float* W1   = (const float*)d_in[15];
  const float* b1   = (const float*)d_in[16];
  const float* Wm   = (const float*)d_in[17];
  const float* bm   = (const float*)d_in[18];
  const float* W2   = (const float*)d_in[19];
  const float* b2   = (const float*)d_in[20];
  const float* Wout = (const float*)d_in[21];
  const float* bout = (const float*)d_in[22];
  float* logits = (float*)d_out;

  const int M = B_ * S_;  // 4096
  float* ws = (float*)d_ws;
  float* h    = ws;                                   // fp32 [M][D]
  float* bqkv = h + (size_t)M * D_;                   // fp32 [L][1536]
  __bf16* y16  = (__bf16*)(bqkv + (size_t)L_ * 1536);
  __bf16* f1b  = y16  + (size_t)M * D_;
  __bf16* f2b  = f1b  + (size_t)M * DFF_;
  __bf16* qb16 = f2b  + (size_t)M * DFF_;
  __bf16* kb16 = qb16 + (size_t)M * D_;
  __bf16* vt16 = kb16 + (size_t)M * D_;               // [B][D][S]
  __bf16* ob16 = vt16 + (size_t)M * D_;
  __bf16* h16  = ob16 + (size_t)M * D_;
  __bf16* WqkvT = h16 + (size_t)M * D_;               // [l][1536][512]
  __bf16* WoT  = WqkvT + (size_t)L_ * 1536 * D_;
  __bf16* W1T  = WoT  + (size_t)L_ * D_ * D_;         // [l][DFF][D]
  __bf16* WmT  = W1T  + (size_t)L_ * D_ * DFF_;       // [l][DFF][DFF]
  __bf16* W2T  = WmT  + (size_t)L_ * DFF_ * DFF_;     // [l][D][DFF]
  __bf16* WoutT = W2T + (size_t)L_ * D_ * DFF_;       // [V][D]

  const long DD = (long)D_ * D_;
  transpose_bf16_kernel<<<dim3(D_/32,  D_/32,   L_), 256, 0, stream>>>(Wq, WqkvT,            D_, D_, DD, 1536L*D_);
  transpose_bf16_kernel<<<dim3(D_/32,  D_/32,   L_), 256, 0, stream>>>(Wk, WqkvT + 512*512,  D_, D_, DD, 1536L*D_);
  transpose_bf16_kernel<<<dim3(D_/32,  D_/32,   L_), 256, 0, stream>>>(Wv, WqkvT + 1024*512, D_, D_, DD, 1536L*D_);
  transpose_bf16_kernel<<<dim3(D_/32,  D_/32,   L_), 256, 0, stream>>>(Wo, WoT, D_, D_, DD, DD);
  transpose_bf16_kernel<<<dim3(DFF_/32, D_/32,  L_), 256, 0, stream>>>(W1, W1T, D_, DFF_, (long)D_*DFF_, (long)D_*DFF_);
  transpose_bf16_kernel<<<dim3(DFF_/32, DFF_/32,L_), 256, 0, stream>>>(Wm, WmT, DFF_, DFF_, (long)DFF_*DFF_, (long)DFF_*DFF_);
  transpose_bf16_kernel<<<dim3(D_/32,  DFF_/32, L_), 256, 0, stream>>>(W2, W2T, DFF_, D_, (long)D_*DFF_, (long)D_*DFF_);
  transpose_bf16_kernel<<<dim3(V_/32,  D_/32,   1 ), 256, 0, stream>>>(Wout, WoutT, D_, V_, (long)D_*V_, (long)D_*V_);
  concat_bias_kernel<<<(L_*1536)/256, 256, 0, stream>>>(bq, bk, bv, bqkv);

  embed_kernel<<<M, 128, 0, stream>>>(x, tok, pos, h);

  for (int l = 0; l < L_; ++l) {
    ln_kernel<<<M, 256, 0, stream>>>(h, g1 + l * D_, be1 + l * D_, y16);
    gemm_bf16_kernel<4,false,false><<<dim3(M/BM, 1536/BN), 256, 0, stream>>>(
        y16, WqkvT + (size_t)l * 1536 * D_, bqkv + l * 1536, nullptr,
        qb16, kb16, vt16, M, 1536, D_);
    attn_kernel<<<dim3(S_/16, H_, B_), 256, 0, stream>>>(qb16, kb16, vt16, ob16);
    gemm_bf16_kernel<0,false,true><<<dim3(M/BM, D_/BN), 256, 0, stream>>>(
        ob16, WoT + (size_t)l * DD, bo + l * D_, h, h, nullptr, nullptr, M, D_, D_);
    ln_kernel<<<M, 256, 0, stream>>>(h, g2 + l * D_, be2 + l * D_, y16);
    gemm_bf16_kernel<1,true,false><<<dim3(M/BM, DFF_/BN), 256, 0, stream>>>(
        y16, W1T + (size_t)l * D_ * DFF_, b1 + l * DFF_, nullptr, f1b, nullptr, nullptr, M, DFF_, D_);
    gemm_bf16_kernel<1,true,false><<<dim3(M/BM, DFF_/BN), 256, 0, stream>>>(
        f1b, WmT + (size_t)l * DFF_ * DFF_, bm + l * DFF_, nullptr, f2b, nullptr, nullptr, M, DFF_, DFF_);
    gemm_bf16_kernel<3,false,true><<<dim3(M/BM, D_/BN), 256, 0, stream>>>(
        f2b, W2T + (size_t)l * D_ * DFF_, b2 + l * D_, h, h, h16, nullptr, M, D_, DFF_);
  }
  gemm_bf16_kernel<0,false,false><<<dim3(M/BM, V_/BN), 256, 0, stream>>>(
      h16, WoutT, bout, nullptr, logits, nullptr, nullptr, M, V_, D_);
}

// Round 4
// 1670.336 us; speedup vs baseline: 1.8354x; 1.0032x over previous
//
#include <hip/hip_runtime.h>
#include <hip/hip_bf16.h>
#include <math.h>

#define B_ 4
#define S_ 1024
#define D_ 512
#define H_ 8
#define L_ 4
#define DFF_ 2048
#define V_ 32000
#define DK_ 64
#define KTOP 307
#define QR 8        // q-rows per attention block
#define PST 1048    // P overlay row stride (bf16 elems) -> 524 words = 12 mod 32 banks

using bf16x8 = __attribute__((ext_vector_type(8))) __bf16;
using bf16x4 = __attribute__((ext_vector_type(4))) __bf16;
using bf16x2 = __attribute__((ext_vector_type(2))) __bf16;
using f32x4v = __attribute__((ext_vector_type(4))) float;

__device__ __forceinline__ void gload_lds16(const __bf16* g, __bf16* l) {
  __builtin_amdgcn_global_load_lds(
      (const __attribute__((address_space(1))) void*)g,
      (__attribute__((address_space(3))) void*)l, 16, 0, 0);
}

// ---------------- embedding: h = tok_emb[x] + pos_emb ----------------
__global__ void embed_kernel(const int* __restrict__ x, const float* __restrict__ tok,
                             const float* __restrict__ pos, float* __restrict__ h) {
  int row = blockIdx.x;
  int t = threadIdx.x;             // 128 threads x float4 = 512
  int s = row & (S_ - 1);
  int token = x[row];
  const float4* t4 = reinterpret_cast<const float4*>(tok + (size_t)token * D_);
  const float4* p4 = reinterpret_cast<const float4*>(pos + (size_t)s * D_);
  float4 a = t4[t];
  float4 b = p4[t];
  a.x += b.x; a.y += b.y; a.z += b.z; a.w += b.w;
  reinterpret_cast<float4*>(h + (size_t)row * D_)[t] = a;
}

// ---------------- layernorm (one block per row, D=512), bf16 out ----------------
__global__ void ln_kernel(const float* __restrict__ xin, const float* __restrict__ g,
                          const float* __restrict__ bta, __bf16* __restrict__ y) {
  int row = blockIdx.x;
  int t = threadIdx.x;             // 256 threads x float2
  const float2* x2 = reinterpret_cast<const float2*>(xin + (size_t)row * D_);
  float2 v = x2[t];
  float s = v.x + v.y;
  #pragma unroll
  for (int m = 1; m < 64; m <<= 1) s += __shfl_xor(s, m, 64);
  __shared__ float red[4];
  __shared__ float red2[4];
  int wid = t >> 6, lane = t & 63;
  if (lane == 0) red[wid] = s;
  __syncthreads();
  float mu = (red[0] + red[1] + red[2] + red[3]) * (1.0f / D_);
  float dx = v.x - mu, dy = v.y - mu;
  float s2 = dx * dx + dy * dy;
  #pragma unroll
  for (int m = 1; m < 64; m <<= 1) s2 += __shfl_xor(s2, m, 64);
  if (lane == 0) red2[wid] = s2;
  __syncthreads();
  float var = (red2[0] + red2[1] + red2[2] + red2[3]) * (1.0f / D_);
  float rstd = rsqrtf(var + 1e-5f);
  float2 gg = reinterpret_cast<const float2*>(g)[t];
  float2 bb = reinterpret_cast<const float2*>(bta)[t];
  bf16x2 o2;
  o2[0] = (__bf16)(dx * rstd * gg.x + bb.x);
  o2[1] = (__bf16)(dy * rstd * gg.y + bb.y);
  *reinterpret_cast<bf16x2*>(y + (size_t)row * D_ + t * 2) = o2;
}

// ------------- transpose fp32 [Kd][N] -> bf16 [N][Kd], batched over z -------------
__global__ void transpose_bf16_kernel(const float* __restrict__ in, __bf16* __restrict__ out,
                                      int Kd, int N, long in_bstride, long out_bstride) {
  __shared__ float tile[32][33];
  const float* ib = in + (size_t)blockIdx.z * in_bstride;
  __bf16* ob = out + (size_t)blockIdx.z * out_bstride;
  int n0 = blockIdx.x * 32, k0 = blockIdx.y * 32;
  int tx = threadIdx.x & 31, ty = threadIdx.x >> 5;   // 32x8
  #pragma unroll
  for (int i = 0; i < 4; ++i)
    tile[ty + i * 8][tx] = ib[(size_t)(k0 + ty + i * 8) * N + n0 + tx];
  __syncthreads();
  #pragma unroll
  for (int i = 0; i < 4; ++i)
    ob[(size_t)(n0 + ty + i * 8) * Kd + k0 + tx] = (__bf16)tile[tx][ty + i * 8];
}

// ---------------- bias concat for fused QKV ----------------
__global__ void concat_bias_kernel(const float* __restrict__ bq, const float* __restrict__ bk,
                                   const float* __restrict__ bv, float* __restrict__ bqkv) {
  int i = blockIdx.x * 256 + threadIdx.x;   // L_*1536
  int l = i / 1536, c = i - l * 1536;
  float v = (c < 512) ? bq[l * 512 + c]
          : (c < 1024) ? bk[l * 512 + c - 512]
                       : bv[l * 512 + c - 1024];
  bqkv[i] = v;
}

// ---------------- bf16 MFMA GEMM (m97 structure), 128x128 tile ----------------
// OMODE: 0 fp32 out | 1 bf16 out | 3 fp32 out + bf16 out2 | 4 fused-QKV
#define BM 128
#define BN 128
#define BK 32

template<int OMODE, bool GELU_ACT, bool RES, bool SWZ>
__global__ __launch_bounds__(256)
void gemm_bf16_kernel(const __bf16* __restrict__ A, const __bf16* __restrict__ WT,
                      const float* __restrict__ bias, const float* __restrict__ res,
                      void* __restrict__ outp, void* __restrict__ outp2, void* __restrict__ outp3,
                      int M, int N, int Kd) {
  __shared__ __bf16 As[BM * BK];
  __shared__ __bf16 Ws[BN * BK];
  int tid = threadIdx.x;
  int lane = tid & 63, w = tid >> 6;
  int wr = w >> 1, wc = w & 1;
  int lr = lane & 15, lg = lane >> 4;
  int bx, by;
  if (SWZ) {   // XCD-bijective swizzle (nwg % 8 == 0): consecutive swz on one XCD
    int lid = blockIdx.x;
    int cpx = gridDim.x >> 3;
    int swz = (lid & 7) * cpx + (lid >> 3);
    int gx = M >> 7;
    bx = swz % gx;
    by = swz / gx;
  } else {
    bx = blockIdx.x; by = blockIdx.y;
  }
  int row0 = bx * BM, col0 = by * BN;

  int srow = lane >> 2;        // 0..15 row within 16-row stripe
  int schunk = lane & 3;       // 16B chunk within a 64B row
  const __bf16* Abase = A + (size_t)(row0 + srow) * Kd + schunk * 8;
  const __bf16* Wbase = WT + (size_t)(col0 + srow) * Kd + schunk * 8;

  f32x4v acc[4][4];
  #pragma unroll
  for (int i = 0; i < 4; ++i)
    #pragma unroll
    for (int j = 0; j < 4; ++j)
      #pragma unroll
      for (int e = 0; e < 4; ++e) acc[i][j][e] = 0.0f;

  for (int k0 = 0; k0 < Kd; k0 += BK) {
    #pragma unroll
    for (int p = 0; p < 2; ++p) {
      int r0 = p * 64 + w * 16;
      gload_lds16(Abase + (size_t)r0 * Kd + k0, &As[r0 * BK]);
      gload_lds16(Wbase + (size_t)r0 * Kd + k0, &Ws[r0 * BK]);
    }
    __syncthreads();
    bf16x8 af[4], bfr[4];
    #pragma unroll
    for (int mr = 0; mr < 4; ++mr)
      af[mr] = *reinterpret_cast<const bf16x8*>(&As[(wr * 64 + mr * 16 + lr) * BK + lg * 8]);
    #pragma unroll
    for (int nc = 0; nc < 4; ++nc)
      bfr[nc] = *reinterpret_cast<const bf16x8*>(&Ws[(wc * 64 + nc * 16 + lr) * BK + lg * 8]);
    #pragma unroll
    for (int mr = 0; mr < 4; ++mr)
      #pragma unroll
      for (int nc = 0; nc < 4; ++nc)
        acc[mr][nc] = __builtin_amdgcn_mfma_f32_16x16x32_bf16(af[mr], bfr[nc], acc[mr][nc], 0, 0, 0);
    __syncthreads();
  }

  #pragma unroll
  for (int mr = 0; mr < 4; ++mr) {
    #pragma unroll
    for (int nc = 0; nc < 4; ++nc) {
      int c = col0 + wc * 64 + nc * 16 + lr;
      int rb = row0 + wr * 64 + mr * 16 + lg * 4;
      float vv[4];
      #pragma unroll
      for (int j = 0; j < 4; ++j) {
        float t = acc[mr][nc][j] + bias[c];
        if (RES) t += res[(size_t)(rb + j) * N + c];
        if (GELU_ACT) t = 0.5f * t * (1.0f + erff(t * 0.70710678118654752f));
        vv[j] = t;
      }
      if (OMODE == 0) {
        float* out = (float*)outp;
        #pragma unroll
        for (int j = 0; j < 4; ++j) out[(size_t)(rb + j) * N + c] = vv[j];
      } else if (OMODE == 1) {
        __bf16* out = (__bf16*)outp;
        #pragma unroll
        for (int j = 0; j < 4; ++j) out[(size_t)(rb + j) * N + c] = (__bf16)vv[j];
      } else if (OMODE == 3) {
        float* out = (float*)outp;
        __bf16* out2 = (__bf16*)outp2;
        #pragma unroll
        for (int j = 0; j < 4; ++j) {
          out[(size_t)(rb + j) * N + c] = vv[j];
          out2[(size_t)(rb + j) * N + c] = (__bf16)vv[j];
        }
      } else {  // OMODE 4: fused QKV epilogue
        if (col0 < 512) {
          __bf16* out = (__bf16*)outp;
          #pragma unroll
          for (int j = 0; j < 4; ++j) out[(size_t)(rb + j) * D_ + c] = (__bf16)vv[j];
        } else if (col0 < 1024) {
          __bf16* out = (__bf16*)outp2;
          #pragma unroll
          for (int j = 0; j < 4; ++j) out[(size_t)(rb + j) * D_ + (c - 512)] = (__bf16)vv[j];
        } else {
          __bf16* out = (__bf16*)outp3;   // vt [B][D][S]
          int b = rb >> 10, s0 = rb & (S_ - 1);
          bf16x4 pk;
          #pragma unroll
          for (int j = 0; j < 4; ++j) pk[j] = (__bf16)vv[j];
          *reinterpret_cast<bf16x4*>(&out[((size_t)b * D_ + (c - 1024)) * S_ + s0]) = pk;
        }
      }
    }
  }
}

// ---------------- 64x128-tile GEMM for N=512 shapes (Wo, W2) -> 256 workgroups ----------------
template<int OMODE, bool RES>
__global__ __launch_bounds__(256)
void gemm64_kernel(const __bf16* __restrict__ A, const __bf16* __restrict__ WT,
                   const float* __restrict__ bias, const float* __restrict__ res,
                   void* __restrict__ outp, void* __restrict__ outp2,
                   int M, int N, int Kd) {
  __shared__ __bf16 As[64 * BK];
  __shared__ __bf16 Ws[BN * BK];
  int tid = threadIdx.x;
  int lane = tid & 63, w = tid >> 6;
  int wr = w >> 1, wc = w & 1;              // 2x2 waves, each 32x64
  int lr = lane & 15, lg = lane >> 4;
  int row0 = blockIdx.x * 64, col0 = blockIdx.y * BN;

  int srow = lane >> 2;
  int schunk = lane & 3;
  const __bf16* Abase = A + (size_t)(row0 + srow) * Kd + schunk * 8;
  const __bf16* Wbase = WT + (size_t)(col0 + srow) * Kd + schunk * 8;

  f32x4v acc[2][4];
  #pragma unroll
  for (int i = 0; i < 2; ++i)
    #pragma unroll
    for (int j = 0; j < 4; ++j)
      #pragma unroll
      for (int e = 0; e < 4; ++e) acc[i][j][e] = 0.0f;

  for (int k0 = 0; k0 < Kd; k0 += BK) {
    gload_lds16(Abase + (size_t)(w * 16) * Kd + k0, &As[w * 16 * BK]);
    #pragma unroll
    for (int p = 0; p < 2; ++p) {
      int r0 = p * 64 + w * 16;
      gload_lds16(Wbase + (size_t)r0 * Kd + k0, &Ws[r0 * BK]);
    }
    __syncthreads();
    bf16x8 af[2], bfr[4];
    #pragma unroll
    for (int mr = 0; mr < 2; ++mr)
      af[mr] = *reinterpret_cast<const bf16x8*>(&As[(wr * 32 + mr * 16 + lr) * BK + lg * 8]);
    #pragma unroll
    for (int nc = 0; nc < 4; ++nc)
      bfr[nc] = *reinterpret_cast<const bf16x8*>(&Ws[(wc * 64 + nc * 16 + lr) * BK + lg * 8]);
    #pragma unroll
    for (int mr = 0; mr < 2; ++mr)
      #pragma unroll
      for (int nc = 0; nc < 4; ++nc)
        acc[mr][nc] = __builtin_amdgcn_mfma_f32_16x16x32_bf16(af[mr], bfr[nc], acc[mr][nc], 0, 0, 0);
    __syncthreads();
  }

  #pragma unroll
  for (int mr = 0; mr < 2; ++mr) {
    #pragma unroll
    for (int nc = 0; nc < 4; ++nc) {
      int c = col0 + wc * 64 + nc * 16 + lr;
      int rb = row0 + wr * 32 + mr * 16 + lg * 4;
      float vv[4];
      #pragma unroll
      for (int j = 0; j < 4; ++j) {
        float t = acc[mr][nc][j] + bias[c];
        if (RES) t += res[(size_t)(rb + j) * N + c];
        vv[j] = t;
      }
      if (OMODE == 0) {
        float* out = (float*)outp;
        #pragma unroll
        for (int j = 0; j < 4; ++j) out[(size_t)(rb + j) * N + c] = vv[j];
      } else {  // OMODE 3
        float* out = (float*)outp;
        __bf16* out2 = (__bf16*)outp2;
        #pragma unroll
        for (int j = 0; j < 4; ++j) {
          out[(size_t)(rb + j) * N + c] = vv[j];
          out2[(size_t)(rb + j) * N + c] = (__bf16)vv[j];
        }
      }
    }
  }
}

// ---------------- fused attention: MFMA scores -> top-307 -> softmax -> MFMA PV ----------------
// 8 q-rows per block (LDS 33 KB -> 4 blocks/CU), 4 waves, 4096 blocks.
__global__ __launch_bounds__(256)
void attn_kernel(const __bf16* __restrict__ qm, const __bf16* __restrict__ km,
                 const __bf16* __restrict__ vt, __bf16* __restrict__ o) {
  __shared__ unsigned int sc[QR][1036];   // fp32-mapped scores; reused as bf16 P[QR][PST]
  __shared__ float rs[QR];
  const int q0 = blockIdx.x * QR;
  const int hh = blockIdx.y;
  const int bb = blockIdx.z;
  const int tid = threadIdx.x;
  const int lane = tid & 63, w = tid >> 6;
  const int lr = lane & 15, lg = lane >> 4;
  const int qr8 = lr & 7;   // MFMA q-row clamped to the 8 real rows (rows 8-15 duplicate)

  const __bf16* qrow = qm + ((size_t)(bb * S_ + q0 + qr8)) * D_ + hh * DK_;
  bf16x8 qf0 = *reinterpret_cast<const bf16x8*>(qrow + lg * 8);
  bf16x8 qf1 = *reinterpret_cast<const bf16x8*>(qrow + 32 + lg * 8);

  // ---- phase 1: scores via MFMA, K fragments straight from global (L2-resident) ----
  const __bf16* kbase = km + ((size_t)bb * S_) * D_ + hh * DK_;
  #pragma unroll 4
  for (int kt = 0; kt < 16; ++kt) {
    int key0 = kt * 64 + w * 16;
    const __bf16* krow = kbase + (size_t)(key0 + lr) * D_;
    bf16x8 kf0 = *reinterpret_cast<const bf16x8*>(krow + lg * 8);
    bf16x8 kf1 = *reinterpret_cast<const bf16x8*>(krow + 32 + lg * 8);
    f32x4v d = {0.0f, 0.0f, 0.0f, 0.0f};
    __builtin_amdgcn_s_setprio(1);
    d = __builtin_amdgcn_mfma_f32_16x16x32_bf16(qf0, kf0, d, 0, 0, 0);
    d = __builtin_amdgcn_mfma_f32_16x16x32_bf16(qf1, kf1, d, 0, 0, 0);
    __builtin_amdgcn_s_setprio(0);
    if (lg < 2) {   // rows lg*4+j in [0,8)
      #pragma unroll
      for (int j = 0; j < 4; ++j) {
        float s = d[j] * 0.125f;
        unsigned int u = __float_as_uint(s);
        u = (u & 0x80000000u) ? ~u : (u | 0x80000000u);   // monotone map
        sc[lg * 4 + j][key0 + lr] = u;
      }
    }
  }
  __syncthreads();

  // ---- phase 2: per-row top-307 threshold + softmax -> bf16 P (LDS overlay) ----
  {
    int r = tid >> 5, tc = tid & 31;     // 32 threads per row; 8 uint4 groups each
    uint4 uv4[8];
    #pragma unroll
    for (int g = 0; g < 8; ++g)
      uv4[g] = *reinterpret_cast<const uint4*>(&sc[r][tc * 4 + g * 128]);
    __syncthreads();   // scores in registers; sc memory free for P

    unsigned int umax = 0u;
    #pragma unroll
    for (int g = 0; g < 8; ++g) {
      unsigned int m0 = uv4[g].x > uv4[g].y ? uv4[g].x : uv4[g].y;
      unsigned int m1 = uv4[g].z > uv4[g].w ? uv4[g].z : uv4[g].w;
      unsigned int m2 = m0 > m1 ? m0 : m1;
      umax = m2 > umax ? m2 : umax;
    }
    #pragma unroll
    for (int m = 1; m < 32; m <<= 1) {
      unsigned int other = (unsigned int)__shfl_xor((int)umax, m, 64);
      umax = other > umax ? other : umax;
    }
    unsigned int lo = 0u;
    for (int bit = 31; bit >= 0; --bit) {
      unsigned int c = lo | (1u << bit);
      int cnt = 0;
      #pragma unroll
      for (int g = 0; g < 8; ++g) {
        cnt += (uv4[g].x >= c) ? 1 : 0;
        cnt += (uv4[g].y >= c) ? 1 : 0;
        cnt += (uv4[g].z >= c) ? 1 : 0;
        cnt += (uv4[g].w >= c) ? 1 : 0;
      }
      #pragma unroll
      for (int m = 1; m < 32; m <<= 1) cnt += __shfl_xor(cnt, m, 64);
      if (cnt >= KTOP) lo = c;
    }
    unsigned int ubm = (umax & 0x80000000u) ? (umax ^ 0x80000000u) : ~umax;
    float mval = __uint_as_float(ubm);

    __bf16* P = reinterpret_cast<__bf16*>(&sc[0][0]);   // [QR][PST]
    float lsum = 0.0f;
    #pragma unroll
    for (int g = 0; g < 8; ++g) {
      unsigned int uu[4] = {uv4[g].x, uv4[g].y, uv4[g].z, uv4[g].w};
      bf16x4 pk;
      #pragma unroll
      for (int e = 0; e < 4; ++e) {
        float p = 0.0f;
        if (uu[e] >= lo) {
          unsigned int ub = (uu[e] & 0x80000000u) ? (uu[e] ^ 0x80000000u) : ~uu[e];
          p = __expf(__uint_as_float(ub) - mval);
        }
        pk[e] = (__bf16)p;
        lsum += (float)pk[e];
      }
      *reinterpret_cast<bf16x4*>(&P[(size_t)r * PST + tc * 4 + g * 128]) = pk;
    }
    #pragma unroll
    for (int m = 1; m < 32; m <<= 1) lsum += __shfl_xor(lsum, m, 64);
    if (tc == 0) rs[r] = lsum;
  }
  __syncthreads();

  // ---- phase 3: o = (P @ V) / rowsum via MFMA; V^T fragments straight from global ----
  {
    const __bf16* P = reinterpret_cast<const __bf16*>(&sc[0][0]);
    const __bf16* vbase = vt + ((size_t)bb * D_ + hh * DK_ + w * 16 + lr) * S_;
    const __bf16* prow = P + (size_t)qr8 * PST;
    f32x4v oacc = {0.0f, 0.0f, 0.0f, 0.0f};
    #pragma unroll 4
    for (int kt = 0; kt < 32; ++kt) {
      bf16x8 a = *reinterpret_cast<const bf16x8*>(prow + kt * 32 + lg * 8);
      bf16x8 b = *reinterpret_cast<const bf16x8*>(vbase + kt * 32 + lg * 8);
      __builtin_amdgcn_s_setprio(1);
      oacc = __builtin_amdgcn_mfma_f32_16x16x32_bf16(a, b, oacc, 0, 0, 0);
      __builtin_amdgcn_s_setprio(0);
    }
    if (lg < 2) {
      #pragma unroll
      for (int j = 0; j < 4; ++j) {
        int qr = lg * 4 + j;
        float ov = oacc[j] / rs[qr];
        o[((size_t)(bb * S_ + q0 + qr)) * D_ + hh * DK_ + w * 16 + lr] = (__bf16)ov;
      }
    }
  }
}

extern "C" void kernel_launch(void* const* d_in, const int* in_sizes, int n_in,
                              void* d_out, int out_size, void* d_ws, size_t ws_size,
                              hipStream_t stream) {
  (void)in_sizes; (void)n_in; (void)out_size; (void)ws_size;
  const int*   x    = (const int*)d_in[0];
  const float* tok  = (const float*)d_in[1];
  const float* pos  = (const float*)d_in[2];
  const float* Wq   = (const float*)d_in[3];
  const float* bq   = (const float*)d_in[4];
  const float* Wk   = (const float*)d_in[5];
  const float* bk   = (const float*)d_in[6];
  const float* Wv   = (const float*)d_in[7];
  const float* bv   = (const float*)d_in[8];
  const float* Wo   = (const float*)d_in[9];
  const float* bo   = (const float*)d_in[10];
  const float* g1   = (const float*)d_in[11];
  const float* be1  = (const float*)d_in[12];
  const float* g2   = (const float*)d_in[13];
  const float* be2  = (const float*)d_in[14];
  const float* W1   = (const float*)d_in[15];
  const float* b1   = (const float*)d_in[16];
  const float* Wm   = (const float*)d_in[17];
  const float* bm   = (const float*)d_in[18];
  const float* W2   = (const float*)d_in[19];
  const float* b2   = (const float*)d_in[20];
  const float* Wout = (const float*)d_in[21];
  const float* bout = (const float*)d_in[22];
  float* logits = (float*)d_out;

  const int M = B_ * S_;  // 4096
  float* ws = (float*)d_ws;
  float* h    = ws;                                   // fp32 [M][D]
  float* bqkv = h + (size_t)M * D_;                   // fp32 [L][1536]
  __bf16* y16  = (__bf16*)(bqkv + (size_t)L_ * 1536);
  __bf16* f1b  = y16  + (size_t)M * D_;
  __bf16* f2b  = f1b  + (size_t)M * DFF_;
  __bf16* qb16 = f2b  + (size_t)M * DFF_;
  __bf16* kb16 = qb16 + (size_t)M * D_;
  __bf16* vt16 = kb16 + (size_t)M * D_;               // [B][D][S]
  __bf16* ob16 = vt16 + (size_t)M * D_;
  __bf16* h16  = ob16 + (size_t)M * D_;
  __bf16* WqkvT = h16 + (size_t)M * D_;               // [l][1536][512]
  __bf16* WoT  = WqkvT + (size_t)L_ * 1536 * D_;
  __bf16* W1T  = WoT  + (size_t)L_ * D_ * D_;         // [l][DFF][D]
  __bf16* WmT  = W1T  + (size_t)L_ * D_ * DFF_;       // [l][DFF][DFF]
  __bf16* W2T  = WmT  + (size_t)L_ * DFF_ * DFF_;     // [l][D][DFF]
  __bf16* WoutT = W2T + (size_t)L_ * D_ * DFF_;       // [V][D]

  const long DD = (long)D_ * D_;
  transpose_bf16_kernel<<<dim3(D_/32,  D_/32,   L_), 256, 0, stream>>>(Wq, WqkvT,            D_, D_, DD, 1536L*D_);
  transpose_bf16_kernel<<<dim3(D_/32,  D_/32,   L_), 256, 0, stream>>>(Wk, WqkvT + 512*512,  D_, D_, DD, 1536L*D_);
  transpose_bf16_kernel<<<dim3(D_/32,  D_/32,   L_), 256, 0, stream>>>(Wv, WqkvT + 1024*512, D_, D_, DD, 1536L*D_);
  transpose_bf16_kernel<<<dim3(D_/32,  D_/32,   L_), 256, 0, stream>>>(Wo, WoT, D_, D_, DD, DD);
  transpose_bf16_kernel<<<dim3(DFF_/32, D_/32,  L_), 256, 0, stream>>>(W1, W1T, D_, DFF_, (long)D_*DFF_, (long)D_*DFF_);
  transpose_bf16_kernel<<<dim3(DFF_/32, DFF_/32,L_), 256, 0, stream>>>(Wm, WmT, DFF_, DFF_, (long)DFF_*DFF_, (long)DFF_*DFF_);
  transpose_bf16_kernel<<<dim3(D_/32,  DFF_/32, L_), 256, 0, stream>>>(W2, W2T, DFF_, D_, (long)D_*DFF_, (long)D_*DFF_);
  transpose_bf16_kernel<<<dim3(V_/32,  D_/32,   1 ), 256, 0, stream>>>(Wout, WoutT, D_, V_, (long)D_*V_, (long)D_*V_);
  concat_bias_kernel<<<(L_*1536)/256, 256, 0, stream>>>(bq, bk, bv, bqkv);

  embed_kernel<<<M, 128, 0, stream>>>(x, tok, pos, h);

  for (int l = 0; l < L_; ++l) {
    ln_kernel<<<M, 256, 0, stream>>>(h, g1 + l * D_, be1 + l * D_, y16);
    gemm_bf16_kernel<4,false,false,false><<<dim3(M/BM, 1536/BN), 256, 0, stream>>>(
        y16, WqkvT + (size_t)l * 1536 * D_, bqkv + l * 1536, nullptr,
        qb16, kb16, vt16, M, 1536, D_);
    attn_kernel<<<dim3(S_/QR, H_, B_), 256, 0, stream>>>(qb16, kb16, vt16, ob16);
    gemm64_kernel<0,true><<<dim3(M/64, D_/BN), 256, 0, stream>>>(
        ob16, WoT + (size_t)l * DD, bo + l * D_, h, h, nullptr, M, D_, D_);
    ln_kernel<<<M, 256, 0, stream>>>(h, g2 + l * D_, be2 + l * D_, y16);
    gemm_bf16_kernel<1,true,false,false><<<dim3(M/BM, DFF_/BN), 256, 0, stream>>>(
        y16, W1T + (size_t)l * D_ * DFF_, b1 + l * DFF_, nullptr, f1b, nullptr, nullptr, M, DFF_, D_);
    gemm_bf16_kernel<1,true,false,false><<<dim3(M/BM, DFF_/BN), 256, 0, stream>>>(
        f1b, WmT + (size_t)l * DFF_ * DFF_, bm + l * DFF_, nullptr, f2b, nullptr, nullptr, M, DFF_, DFF_);
    gemm64_kernel<3,true><<<dim3(M/64, D_/BN), 256, 0, stream>>>(
        f2b, W2T + (size_t)l * D_ * DFF_, b2 + l * D_, h, h, h16, M, D_, DFF_);
  }
  gemm_bf16_kernel<0,false,false,true><<<dim3((M/BM) * (V_/BN)), 256, 0, stream>>>(
      h16, WoutT, bout, nullptr, logits, nullptr, nullptr, M, V_, D_);
}